// Round 5
// baseline (399.931 us; speedup 1.0000x reference)
//
#include <hip/hip_runtime.h>
#include <math.h>

// GraphAttentionLayer:
//   Wh = X @ W ; f = Wh @ a1 ; g = Wh @ a2
//   attention = softmax(leaky_relu(f[:,None] + g[None,:]), axis=1)
// Reassociated: f = X @ (W@a1), g = X @ (W@a2).  adj is unused by the reference.
// leaky_relu is monotone => row max = lrelu(f_i + max(g)).
//
// 3-dispatch pipeline, NO cross-block atomics (round-3 post-mortem: 2048
// same-address device-scope atomicMax cost +18 µs):
//   k_wa:   wa1/wa2 = W@a1, W@a2.
//   k_fg:   f,g per row (one wave per row).
//   k_attn: R=4 rows per block. g loaded into 32 VGPRs ONCE and max-reduced
//           ONCE per block (row-invariant), reused for all 4 rows; exps
//           computed once per output element into a second reg set; scaled
//           nontemporal stores. Row loop unrolled so row r's stores overlap
//           row r+1's exp VALU.

static constexpr float ALPHA = 0.2f;
static constexpr int N    = 8192;
static constexpr int FIN  = 512;
static constexpr int FOUT = 256;

typedef float v4f __attribute__((ext_vector_type(4)));

__device__ __forceinline__ float lrelu(float x) {
    // for 0<ALPHA<1: lrelu(x) == max(x, ALPHA*x)
    return fmaxf(x, ALPHA * x);
}

// ---------------- Kernel A: wa1[k] = sum_j W[k,j]*a[j]; wa2[k] = sum_j W[k,j]*a[FOUT+j]
// grid = FIN blocks x 64 threads (one wave per W row)
__global__ void k_wa(const float* __restrict__ W, const float* __restrict__ a,
                     float* __restrict__ wa1, float* __restrict__ wa2) {
    const int k    = blockIdx.x;
    const int lane = threadIdx.x;
    const float* row = W + (size_t)k * FOUT;
    float s1 = 0.0f, s2 = 0.0f;
    for (int j = lane; j < FOUT; j += 64) {
        const float w = row[j];
        s1 += w * a[j];
        s2 += w * a[FOUT + j];
    }
    #pragma unroll
    for (int off = 32; off > 0; off >>= 1) {
        s1 += __shfl_down(s1, off, 64);
        s2 += __shfl_down(s2, off, 64);
    }
    if (lane == 0) { wa1[k] = s1; wa2[k] = s2; }
}

// ---------------- Kernel B: f[i] = dot(X[i,:], wa1); g[i] = dot(X[i,:], wa2)
// one wave per row; 4 waves/block; grid exactly N/4 blocks.
__global__ __launch_bounds__(256) void k_fg(const float* __restrict__ X,
                                            const float* __restrict__ wa1,
                                            const float* __restrict__ wa2,
                                            float* __restrict__ f,
                                            float* __restrict__ g) {
    const int gid  = blockIdx.x * blockDim.x + threadIdx.x;
    const int row  = gid >> 6;
    const int lane = threadIdx.x & 63;
    const float4* x4  = (const float4*)(X + (size_t)row * FIN);
    const float4* w14 = (const float4*)wa1;
    const float4* w24 = (const float4*)wa2;
    float s1 = 0.0f, s2 = 0.0f;
    #pragma unroll
    for (int k4 = lane; k4 < (FIN >> 2); k4 += 64) {
        const float4 v  = x4[k4];
        const float4 w1 = w14[k4];
        const float4 w2 = w24[k4];
        s1 += v.x*w1.x + v.y*w1.y + v.z*w1.z + v.w*w1.w;
        s2 += v.x*w2.x + v.y*w2.y + v.z*w2.z + v.w*w2.w;
    }
    #pragma unroll
    for (int off = 32; off > 0; off >>= 1) {
        s1 += __shfl_down(s1, off, 64);
        s2 += __shfl_down(s2, off, 64);
    }
    if (lane == 0) { f[row] = s1; g[row] = s2; }
}

// ---------------- Kernel C: per-row softmax of lrelu(f_i + g_j), R rows/block
// 256 threads; each thread owns 8 float4 (32 cols) of g in registers.
__global__ __launch_bounds__(256) void k_attn(const float* __restrict__ f,
                                              const float* __restrict__ g,
                                              float* __restrict__ out) {
    constexpr int R  = 4;
    constexpr int n4 = N >> 2;        // 2048
    constexpr int PT = n4 / 256;      // 8 float4 per thread = 32 VGPRs
    const int i0 = blockIdx.x * R;

    const float4* g4 = (const float4*)g;

    // Phase 1: load g into regs, block-reduce max(g) — ONCE per block
    float4 p[PT];
    float pm = -INFINITY;
    #pragma unroll
    for (int t = 0; t < PT; ++t) {
        const float4 gv = g4[threadIdx.x + t * 256];
        p[t] = gv;
        pm = fmaxf(fmaxf(pm, fmaxf(gv.x, gv.y)), fmaxf(gv.z, gv.w));
    }
    __shared__ float smx[4];
    __shared__ float sms[R][4];
    #pragma unroll
    for (int off = 32; off > 0; off >>= 1) pm = fmaxf(pm, __shfl_down(pm, off, 64));
    if ((threadIdx.x & 63) == 0) smx[threadIdx.x >> 6] = pm;
    __syncthreads();
    const float gmax = fmaxf(fmaxf(smx[0], smx[1]), fmaxf(smx[2], smx[3]));

    float fr[R];
    #pragma unroll
    for (int r = 0; r < R; ++r) fr[r] = f[i0 + r];

    // Phase 2: per row — exp once into e[] regs, sum-reduce, scale, stream out
    #pragma unroll
    for (int r = 0; r < R; ++r) {
        const float fi = fr[r];
        const float m  = lrelu(fi + gmax);   // row max of e (lrelu monotone)
        float4 e[PT];
        float sum = 0.0f;
        #pragma unroll
        for (int t = 0; t < PT; ++t) {
            float4 ev;
            ev.x = __expf(lrelu(fi + p[t].x) - m);
            ev.y = __expf(lrelu(fi + p[t].y) - m);
            ev.z = __expf(lrelu(fi + p[t].z) - m);
            ev.w = __expf(lrelu(fi + p[t].w) - m);
            sum += (ev.x + ev.y) + (ev.z + ev.w);
            e[t] = ev;
        }
        #pragma unroll
        for (int off = 32; off > 0; off >>= 1) sum += __shfl_down(sum, off, 64);
        if ((threadIdx.x & 63) == 0) sms[r][threadIdx.x >> 6] = sum;
        __syncthreads();
        const float inv = 1.0f /
            ((sms[r][0] + sms[r][1]) + (sms[r][2] + sms[r][3]));

        v4f* out4 = (v4f*)(out + (size_t)(i0 + r) * N);
        #pragma unroll
        for (int t = 0; t < PT; ++t) {
            v4f o;
            o.x = e[t].x * inv;
            o.y = e[t].y * inv;
            o.z = e[t].z * inv;
            o.w = e[t].w * inv;
            __builtin_nontemporal_store(o, &out4[threadIdx.x + t * 256]);
        }
    }
}

extern "C" void kernel_launch(void* const* d_in, const int* in_sizes, int n_in,
                              void* d_out, int out_size, void* d_ws, size_t ws_size,
                              hipStream_t stream) {
    const float* X = (const float*)d_in[0];   // (N, FIN)
    // d_in[1] = adj — unused by the reference computation
    const float* W = (const float*)d_in[2];   // (FIN, FOUT)
    const float* a = (const float*)d_in[3];   // (2*FOUT, 1)
    float* out = (float*)d_out;               // (N, N)

    float* ws  = (float*)d_ws;
    float* wa1 = ws;                 // FIN
    float* wa2 = ws + FIN;           // FIN
    float* f   = ws + 2 * FIN;       // N
    float* g   = ws + 2 * FIN + N;   // N

    k_wa  <<<FIN, 64, 0, stream>>>(W, a, wa1, wa2);
    k_fg  <<<N / 4, 256, 0, stream>>>(X, wa1, wa2, f, g);
    k_attn<<<N / 4, 256, 0, stream>>>(f, g, out);
}

// Round 6
// 396.288 us; speedup vs baseline: 1.0092x; 1.0092x over previous
//
#include <hip/hip_runtime.h>
#include <math.h>

// GraphAttentionLayer:
//   Wh = X @ W ; f = Wh @ a1 ; g = Wh @ a2
//   attention = softmax(leaky_relu(f[:,None] + g[None,:]), axis=1)
// Reassociated: f = X @ (W@a1), g = X @ (W@a2).  adj is unused by the reference.
// leaky_relu is monotone => row max = lrelu(f_i + max(g)).
//
// 3-dispatch pipeline, NO cross-block atomics (round-3: 2048 same-address
// device-scope atomicMax cost +18 µs).  Round-5 lesson: do NOT batch rows
// per block — the extra live register tile (+sync per row) drops occupancy
// and costs more than the saved L2 g-reads.  Keep VGPR <= 64.
//   k_wa:   wa1/wa2 = W@a1, W@a2.
//   k_fg:   f,g per row (one wave per row).
//   k_attn: one row per block, 512 threads (PT=4 -> 16 VGPR tile): shorter
//           per-block serial chain before the sum gate, smoother store issue.

static constexpr float ALPHA = 0.2f;
static constexpr int N    = 8192;
static constexpr int FIN  = 512;
static constexpr int FOUT = 256;

typedef float v4f __attribute__((ext_vector_type(4)));

__device__ __forceinline__ float lrelu(float x) {
    // for 0<ALPHA<1: lrelu(x) == max(x, ALPHA*x)
    return fmaxf(x, ALPHA * x);
}

// ---------------- Kernel A: wa1[k] = sum_j W[k,j]*a[j]; wa2[k] = sum_j W[k,j]*a[FOUT+j]
// grid = FIN blocks x 64 threads (one wave per W row)
__global__ void k_wa(const float* __restrict__ W, const float* __restrict__ a,
                     float* __restrict__ wa1, float* __restrict__ wa2) {
    const int k    = blockIdx.x;
    const int lane = threadIdx.x;
    const float* row = W + (size_t)k * FOUT;
    float s1 = 0.0f, s2 = 0.0f;
    for (int j = lane; j < FOUT; j += 64) {
        const float w = row[j];
        s1 += w * a[j];
        s2 += w * a[FOUT + j];
    }
    #pragma unroll
    for (int off = 32; off > 0; off >>= 1) {
        s1 += __shfl_down(s1, off, 64);
        s2 += __shfl_down(s2, off, 64);
    }
    if (lane == 0) { wa1[k] = s1; wa2[k] = s2; }
}

// ---------------- Kernel B: f[i] = dot(X[i,:], wa1); g[i] = dot(X[i,:], wa2)
// one wave per row; 4 waves/block; grid exactly N/4 blocks.
__global__ __launch_bounds__(256) void k_fg(const float* __restrict__ X,
                                            const float* __restrict__ wa1,
                                            const float* __restrict__ wa2,
                                            float* __restrict__ f,
                                            float* __restrict__ g) {
    const int gid  = blockIdx.x * blockDim.x + threadIdx.x;
    const int row  = gid >> 6;
    const int lane = threadIdx.x & 63;
    const float4* x4  = (const float4*)(X + (size_t)row * FIN);
    const float4* w14 = (const float4*)wa1;
    const float4* w24 = (const float4*)wa2;
    float s1 = 0.0f, s2 = 0.0f;
    #pragma unroll
    for (int k4 = lane; k4 < (FIN >> 2); k4 += 64) {
        const float4 v  = x4[k4];
        const float4 w1 = w14[k4];
        const float4 w2 = w24[k4];
        s1 += v.x*w1.x + v.y*w1.y + v.z*w1.z + v.w*w1.w;
        s2 += v.x*w2.x + v.y*w2.y + v.z*w2.z + v.w*w2.w;
    }
    #pragma unroll
    for (int off = 32; off > 0; off >>= 1) {
        s1 += __shfl_down(s1, off, 64);
        s2 += __shfl_down(s2, off, 64);
    }
    if (lane == 0) { f[row] = s1; g[row] = s2; }
}

// ---------------- Kernel C: per-row softmax of lrelu(f_i + g_j)
// one row per block, 512 threads (8 waves). Each thread owns 4 float4
// (16 cols) of g in registers -> short serial chain before the sum gate.
// Phase 1: load g tile, block-reduce max(g).
// Phase 2: exp in-register (computed once), block-reduce sum.
// Phase 3: scale + nontemporal stores (output never re-read).
__global__ __launch_bounds__(512) void k_attn(const float* __restrict__ f,
                                              const float* __restrict__ g,
                                              float* __restrict__ out) {
    constexpr int T  = 512;
    constexpr int n4 = N >> 2;        // 2048
    constexpr int PT = n4 / T;        // 4 float4 per thread = 16 VGPRs
    const int i = blockIdx.x;
    const float fi = f[i];

    const float4* g4   = (const float4*)g;
    v4f*          out4 = (v4f*)(out + (size_t)i * N);

    // Phase 1: load g tile, track per-thread max
    float4 p[PT];
    float pm = -INFINITY;
    #pragma unroll
    for (int t = 0; t < PT; ++t) {
        const float4 gv = g4[threadIdx.x + t * T];
        p[t] = gv;
        pm = fmaxf(fmaxf(pm, fmaxf(gv.x, gv.y)), fmaxf(gv.z, gv.w));
    }
    __shared__ float smx[8];
    __shared__ float sms[8];
    #pragma unroll
    for (int off = 32; off > 0; off >>= 1) pm = fmaxf(pm, __shfl_down(pm, off, 64));
    if ((threadIdx.x & 63) == 0) smx[threadIdx.x >> 6] = pm;
    __syncthreads();
    const float gmax = fmaxf(fmaxf(fmaxf(smx[0], smx[1]), fmaxf(smx[2], smx[3])),
                             fmaxf(fmaxf(smx[4], smx[5]), fmaxf(smx[6], smx[7])));
    const float m = lrelu(fi + gmax);   // row max of e (lrelu monotone)

    // Phase 2: exps in-register, computed once
    float sum = 0.0f;
    #pragma unroll
    for (int t = 0; t < PT; ++t) {
        float4 e;
        e.x = __expf(lrelu(fi + p[t].x) - m);
        e.y = __expf(lrelu(fi + p[t].y) - m);
        e.z = __expf(lrelu(fi + p[t].z) - m);
        e.w = __expf(lrelu(fi + p[t].w) - m);
        sum += (e.x + e.y) + (e.z + e.w);
        p[t] = e;
    }
    #pragma unroll
    for (int off = 32; off > 0; off >>= 1) sum += __shfl_down(sum, off, 64);
    if ((threadIdx.x & 63) == 0) sms[threadIdx.x >> 6] = sum;
    __syncthreads();
    const float total = ((sms[0] + sms[1]) + (sms[2] + sms[3]))
                      + ((sms[4] + sms[5]) + (sms[6] + sms[7]));
    const float inv = 1.0f / total;

    // Phase 3: scale + streaming store
    #pragma unroll
    for (int t = 0; t < PT; ++t) {
        v4f o;
        o.x = p[t].x * inv;
        o.y = p[t].y * inv;
        o.z = p[t].z * inv;
        o.w = p[t].w * inv;
        __builtin_nontemporal_store(o, &out4[threadIdx.x + t * T]);
    }
}

extern "C" void kernel_launch(void* const* d_in, const int* in_sizes, int n_in,
                              void* d_out, int out_size, void* d_ws, size_t ws_size,
                              hipStream_t stream) {
    const float* X = (const float*)d_in[0];   // (N, FIN)
    // d_in[1] = adj — unused by the reference computation
    const float* W = (const float*)d_in[2];   // (FIN, FOUT)
    const float* a = (const float*)d_in[3];   // (2*FOUT, 1)
    float* out = (float*)d_out;               // (N, N)

    float* ws  = (float*)d_ws;
    float* wa1 = ws;                 // FIN
    float* wa2 = ws + FIN;           // FIN
    float* f   = ws + 2 * FIN;       // N
    float* g   = ws + 2 * FIN + N;   // N

    k_wa  <<<FIN, 64, 0, stream>>>(W, a, wa1, wa2);
    k_fg  <<<N / 4, 256, 0, stream>>>(X, wa1, wa2, f, g);
    k_attn<<<N, 512, 0, stream>>>(f, g, out);
}